// Round 7
// baseline (4074.315 us; speedup 1.0000x reference)
//
#include <hip/hip_runtime.h>

// ---------------------------------------------------------------------------
// AWQ int4 dequant GEMM: out = x @ dequant(qweight, scales, qzeros) + bias
// M=4096, K=4096, N=11008, group=128
//   1) convert_x: fp32->bf16 A[M][K]
//   2) dequant_awq: int4 -> bf16 Bt[N][K]
//   3) gemm_bf16: 256x256, BK=32, 512 thr, LDS 64 KiB -> 2 blocks/CU
//      (4 waves/SIMD TLP covers sync stalls), free-run tile body,
//      XOR-swizzled LDS (chunk ^= (row>>2)&3), XCD cluster mapping, bias fused.
// ---------------------------------------------------------------------------

typedef __bf16 bf16x8 __attribute__((ext_vector_type(8)));
typedef float f32x4 __attribute__((ext_vector_type(4)));
typedef unsigned short ushort8 __attribute__((ext_vector_type(8)));

__device__ __forceinline__ unsigned short f2bf(float f) {
  unsigned int u = __builtin_bit_cast(unsigned int, f);
  u += 0x7FFFu + ((u >> 16) & 1u);
  return (unsigned short)(u >> 16);
}

__device__ __forceinline__ void gload16(const void* g, void* l) {
  __builtin_amdgcn_global_load_lds(
      (const __attribute__((address_space(1))) unsigned int*)g,
      (__attribute__((address_space(3))) unsigned int*)l, 16, 0, 0);
}

// ---------------------------------------------------------------------------
// Kernel 1: x fp32 -> A bf16
// ---------------------------------------------------------------------------
__global__ __launch_bounds__(256) void convert_x(const float* __restrict__ x,
                                                 unsigned short* __restrict__ A,
                                                 long long n8) {
  for (long long idx = (long long)blockIdx.x * 256 + threadIdx.x; idx < n8;
       idx += (long long)gridDim.x * 256) {
    float4 u = ((const float4*)x)[2 * idx];
    float4 v = ((const float4*)x)[2 * idx + 1];
    ushort8 o;
    o[0] = f2bf(u.x); o[1] = f2bf(u.y); o[2] = f2bf(u.z); o[3] = f2bf(u.w);
    o[4] = f2bf(v.x); o[5] = f2bf(v.y); o[6] = f2bf(v.z); o[7] = f2bf(v.w);
    ((ushort8*)A)[idx] = o;
  }
}

// ---------------------------------------------------------------------------
// Kernel 2: AWQ dequant + transpose -> Bt bf16 [N][K]
// ---------------------------------------------------------------------------
__global__ __launch_bounds__(256) void dequant_awq(const int* __restrict__ qw,
                                                   const float* __restrict__ sc,
                                                   const int* __restrict__ qz,
                                                   unsigned short* __restrict__ Bt,
                                                   int K, int N) {
  const int n8w = N >> 3;
  const int tiles_n = N >> 6;
  const int tk = blockIdx.x / tiles_n;
  const int tn = blockIdx.x % tiles_n;
  const int k0 = tk << 6, n0 = tn << 6;
  const int g = k0 >> 7;
  __shared__ unsigned short tile[64][72];
  __shared__ float s_s[64];
  __shared__ float s_z[64];
  const int t = threadIdx.x;
  if (t < 64) {
    s_s[t] = sc[(size_t)g * N + n0 + t];
  } else if (t < 72) {
    const int j = t - 64;
    const int zq = qz[(size_t)g * n8w + (n0 >> 3) + j];
    s_z[j * 8 + 0] = (float)((zq >> 0) & 0xF);
    s_z[j * 8 + 1] = (float)((zq >> 16) & 0xF);
    s_z[j * 8 + 2] = (float)((zq >> 4) & 0xF);
    s_z[j * 8 + 3] = (float)((zq >> 20) & 0xF);
    s_z[j * 8 + 4] = (float)((zq >> 8) & 0xF);
    s_z[j * 8 + 5] = (float)((zq >> 24) & 0xF);
    s_z[j * 8 + 6] = (float)((zq >> 12) & 0xF);
    s_z[j * 8 + 7] = (float)((zq >> 28) & 0xF);
  }
  __syncthreads();
#pragma unroll
  for (int r = 0; r < 2; ++r) {
    const int d = (r << 8) + t;
    const int kk = d >> 3, j = d & 7;
    const int q = qw[(size_t)(k0 + kk) * n8w + (n0 >> 3) + j];
    const int base = j << 3;
    ushort8 o;
    o[0] = f2bf(((float)((q >> 0) & 0xF) - s_z[base + 0]) * s_s[base + 0]);
    o[1] = f2bf(((float)((q >> 16) & 0xF) - s_z[base + 1]) * s_s[base + 1]);
    o[2] = f2bf(((float)((q >> 4) & 0xF) - s_z[base + 2]) * s_s[base + 2]);
    o[3] = f2bf(((float)((q >> 20) & 0xF) - s_z[base + 3]) * s_s[base + 3]);
    o[4] = f2bf(((float)((q >> 8) & 0xF) - s_z[base + 4]) * s_s[base + 4]);
    o[5] = f2bf(((float)((q >> 24) & 0xF) - s_z[base + 5]) * s_s[base + 5]);
    o[6] = f2bf(((float)((q >> 12) & 0xF) - s_z[base + 6]) * s_s[base + 6]);
    o[7] = f2bf(((float)((q >> 28) & 0xF) - s_z[base + 7]) * s_s[base + 7]);
    *(ushort8*)&tile[kk][base] = o;
  }
  __syncthreads();
#pragma unroll
  for (int r = 0; r < 2; ++r) {
    const int d = (r << 8) + t;
    const int nl = d >> 3, seg = d & 7;
    ushort8 o;
#pragma unroll
    for (int i = 0; i < 8; ++i) o[i] = tile[(seg << 3) + i][nl];
    *(ushort8*)&Bt[(size_t)(n0 + nl) * K + k0 + (seg << 3)] = o;
  }
}

// ---------------------------------------------------------------------------
// Kernel 3: 256x256xBK32 bf16 GEMM, 2 blocks/CU.  A [M][K], Bt [N][K].
// 8 waves (2M x 4N), per-wave 128x64 output = acc[8][4] f32x4.
// LDS: 2 bufs x (A[256][32] + B[256][32]) = 64 KiB.
// Swizzle: row of 32 shorts = 4 chunks of 16B; physical chunk = logical ^
// ((row>>2)&3).  Staging pre-swizzles the GLOBAL source (linear LDS dest,
// rule #21); reads apply the same XOR -> 2-way banks max (free).
// Per tile: stage t+1 (4 gload16/thread-wave pattern), 12 ds_read_b128,
// lgkmcnt(0), 32 MFMA, vmcnt(0), barrier.  Cross-block TLP hides stalls.
// ---------------------------------------------------------------------------
#define BM 256
#define BN 256
#define BK 32

__global__ __launch_bounds__(512, 4) void gemm_bf16(const unsigned short* __restrict__ A,
                                                    const unsigned short* __restrict__ Bt,
                                                    const float* __restrict__ bias,
                                                    float* __restrict__ C,
                                                    int M, int N, int K) {
  __shared__ __align__(16) unsigned short sm[2][16384];  // 64 KiB total
  const int tid = threadIdx.x;
  const int w = tid >> 6, lane = tid & 63;
  const int wm = w >> 2, wn = w & 3;

  // cluster mapping (L2 reuse within XCD), as round 6
  const int nbm = M / BM;                       // 16
  const int nbn = N / BN;                       // 43
  const int nclu = ((nbm + 3) >> 2) * ((nbn + 7) >> 3);
  const int xcd = blockIdx.x & 7;
  const int slot = blockIdx.x >> 3;
  const int ci = xcd + 8 * (slot >> 5);
  if (ci >= nclu) return;
  const int t32 = slot & 31;
  const int bm = (ci & 3) * 4 + (t32 & 3);
  const int bn = (ci >> 2) * 8 + (t32 >> 2);
  if (bm >= nbm || bn >= nbn) return;
  const int brow = bm * BM, bcol = bn * BN;

  // staging: wave w covers rows 32w..32w+31 of A and of B (2 gloads each).
  // lane writes LDS bytes base+16*lane -> row base+(lane>>2), phys chunk lane&3.
  // source logical chunk = (lane&3) ^ (lane>>4)  (pre-swizzle).
  const int srow = lane >> 2;
  const int schunk = (lane & 3) ^ (lane >> 4);
  const unsigned short* pA = A + (size_t)(brow + 32 * w + srow) * K + schunk * 8;
  const unsigned short* pB = Bt + (size_t)(bcol + 32 * w + srow) * K + schunk * 8;

  // fragment reads: row r = base + (lane&15), logical chunk = lane>>4,
  // physical chunk = (lane>>4) ^ ((r>>2)&3) = (lane>>4) ^ ((lane&15)>>2).
  const int swz = (lane & 15) >> 2;
  const int aOff = (wm * 128 + (lane & 15)) * 32 + 8 * ((lane >> 4) ^ swz);
  const int bOff = 8192 + (wn * 64 + (lane & 15)) * 32 + 8 * ((lane >> 4) ^ swz);

  const int NKt = K / BK;  // 128

  f32x4 acc[8][4];
#pragma unroll
  for (int m = 0; m < 8; ++m)
#pragma unroll
    for (int n = 0; n < 4; ++n) acc[m][n] = (f32x4){0.f, 0.f, 0.f, 0.f};

  auto stage_tile = [&](int kt) {
    const int buf = kt & 1;
    const int k0 = kt * BK;
    gload16(pA + k0, &sm[buf][1024 * w]);
    gload16(pA + k0 + (size_t)16 * K, &sm[buf][1024 * w + 512]);
    gload16(pB + k0, &sm[buf][8192 + 1024 * w]);
    gload16(pB + k0 + (size_t)16 * K, &sm[buf][8192 + 1024 * w + 512]);
  };

  // prologue
  stage_tile(0);
  asm volatile("s_waitcnt vmcnt(0)" ::: "memory");
  __builtin_amdgcn_s_barrier();

  for (int t = 0; t < NKt; ++t) {
    const unsigned short* bp = sm[t & 1];

    if (t + 1 < NKt) stage_tile(t + 1);
    __builtin_amdgcn_sched_barrier(0);

    bf16x8 a[8], b[4];
#pragma unroll
    for (int m = 0; m < 8; ++m)
      a[m] = *(const bf16x8*)(bp + aOff + 512 * m);
#pragma unroll
    for (int n = 0; n < 4; ++n)
      b[n] = *(const bf16x8*)(bp + bOff + 512 * n);
    asm volatile("s_waitcnt lgkmcnt(0)" ::: "memory");
    __builtin_amdgcn_sched_barrier(0);

    __builtin_amdgcn_s_setprio(1);
#pragma unroll
    for (int m = 0; m < 8; ++m)
#pragma unroll
      for (int n = 0; n < 4; ++n)
        acc[m][n] = __builtin_amdgcn_mfma_f32_16x16x32_bf16(a[m], b[n], acc[m][n], 0, 0, 0);
    __builtin_amdgcn_s_setprio(0);

    // staged data for t+1 landed; all waves' reads already drained
    asm volatile("s_waitcnt vmcnt(0)" ::: "memory");
    __builtin_amdgcn_s_barrier();
  }

  // epilogue: C/D layout col=lane&15, row=(lane>>4)*4+reg
#pragma unroll
  for (int n = 0; n < 4; ++n) {
    const int col = bcol + wn * 64 + n * 16 + (lane & 15);
    const float bv = bias[col];
#pragma unroll
    for (int m = 0; m < 8; ++m) {
      const int row0 = brow + wm * 128 + m * 16 + ((lane >> 4) << 2);
#pragma unroll
      for (int q = 0; q < 4; ++q)
        C[(size_t)(row0 + q) * N + col] = acc[m][n][q] + bv;
    }
  }
}

// ---------------------------------------------------------------------------
extern "C" void kernel_launch(void* const* d_in, const int* in_sizes, int n_in,
                              void* d_out, int out_size, void* d_ws, size_t ws_size,
                              hipStream_t stream) {
  const float* x = (const float*)d_in[0];
  const int* qw = (const int*)d_in[1];
  const float* sc = (const float*)d_in[2];
  const int* qz = (const int*)d_in[3];
  const float* bias = (const float*)d_in[4];
  float* out = (float*)d_out;

  const int N = in_sizes[4];                              // 11008
  const int K = (int)(((long long)in_sizes[1] * 8) / N);  // 4096
  const int M = in_sizes[0] / K;                          // 4096

  const size_t a_elems = (size_t)M * K;
  const size_t b_elems = (size_t)N * K;
  const size_t need = (a_elems + b_elems) * sizeof(unsigned short);
  if (ws_size < need) return;

  unsigned short* A = (unsigned short*)d_ws;
  unsigned short* Bt = A + a_elems;

  convert_x<<<2048, 256, 0, stream>>>(x, A, (long long)(a_elems / 8));
  dequant_awq<<<(K / 64) * (N / 64), 256, 0, stream>>>(qw, sc, qz, Bt, K, N);

  const int nbm = M / BM, nbn = N / BN;
  const int nclu = ((nbm + 3) / 4) * ((nbn + 7) / 8);
  const int grid = 8 * 32 * ((nclu + 7) / 8);
  gemm_bf16<<<grid, 512, 0, stream>>>(A, Bt, bias, out, M, N, K);
}

// Round 8
// 424.930 us; speedup vs baseline: 9.5882x; 9.5882x over previous
//
#include <hip/hip_runtime.h>

// ---------------------------------------------------------------------------
// AWQ int4 dequant GEMM: out = x @ dequant(qweight, scales, qzeros) + bias
// M=4096, K=4096, N=11008, group=128
//   1) convert_x: fp32->bf16 A[M][K]
//   2) dequant_awq: int4 -> bf16 Bt[N][K]
//   3) gemm_bf16: 256x256, BK=32, TRIPLE-buffered LDS (96 KiB), stage 2 tiles
//      ahead, steady-state vmcnt(4) gate (never drains in loop), free-run
//      body w/ counted lgkmcnt, XOR-swizzle (key (row>>1)&3, 2-way=free),
//      XCD cluster mapping, bias fused.  launch_bounds(512,2) (r7 spill fix).
// ---------------------------------------------------------------------------

typedef __bf16 bf16x8 __attribute__((ext_vector_type(8)));
typedef float f32x4 __attribute__((ext_vector_type(4)));
typedef unsigned short ushort8 __attribute__((ext_vector_type(8)));

__device__ __forceinline__ unsigned short f2bf(float f) {
  unsigned int u = __builtin_bit_cast(unsigned int, f);
  u += 0x7FFFu + ((u >> 16) & 1u);
  return (unsigned short)(u >> 16);
}

__device__ __forceinline__ void gload16(const void* g, void* l) {
  __builtin_amdgcn_global_load_lds(
      (const __attribute__((address_space(1))) unsigned int*)g,
      (__attribute__((address_space(3))) unsigned int*)l, 16, 0, 0);
}

// ---------------------------------------------------------------------------
// Kernel 1: x fp32 -> A bf16
// ---------------------------------------------------------------------------
__global__ __launch_bounds__(256) void convert_x(const float* __restrict__ x,
                                                 unsigned short* __restrict__ A,
                                                 long long n8) {
  for (long long idx = (long long)blockIdx.x * 256 + threadIdx.x; idx < n8;
       idx += (long long)gridDim.x * 256) {
    float4 u = ((const float4*)x)[2 * idx];
    float4 v = ((const float4*)x)[2 * idx + 1];
    ushort8 o;
    o[0] = f2bf(u.x); o[1] = f2bf(u.y); o[2] = f2bf(u.z); o[3] = f2bf(u.w);
    o[4] = f2bf(v.x); o[5] = f2bf(v.y); o[6] = f2bf(v.z); o[7] = f2bf(v.w);
    ((ushort8*)A)[idx] = o;
  }
}

// ---------------------------------------------------------------------------
// Kernel 2: AWQ dequant + transpose -> Bt bf16 [N][K]
// ---------------------------------------------------------------------------
__global__ __launch_bounds__(256) void dequant_awq(const int* __restrict__ qw,
                                                   const float* __restrict__ sc,
                                                   const int* __restrict__ qz,
                                                   unsigned short* __restrict__ Bt,
                                                   int K, int N) {
  const int n8w = N >> 3;
  const int tiles_n = N >> 6;
  const int tk = blockIdx.x / tiles_n;
  const int tn = blockIdx.x % tiles_n;
  const int k0 = tk << 6, n0 = tn << 6;
  const int g = k0 >> 7;
  __shared__ unsigned short tile[64][72];
  __shared__ float s_s[64];
  __shared__ float s_z[64];
  const int t = threadIdx.x;
  if (t < 64) {
    s_s[t] = sc[(size_t)g * N + n0 + t];
  } else if (t < 72) {
    const int j = t - 64;
    const int zq = qz[(size_t)g * n8w + (n0 >> 3) + j];
    s_z[j * 8 + 0] = (float)((zq >> 0) & 0xF);
    s_z[j * 8 + 1] = (float)((zq >> 16) & 0xF);
    s_z[j * 8 + 2] = (float)((zq >> 4) & 0xF);
    s_z[j * 8 + 3] = (float)((zq >> 20) & 0xF);
    s_z[j * 8 + 4] = (float)((zq >> 8) & 0xF);
    s_z[j * 8 + 5] = (float)((zq >> 24) & 0xF);
    s_z[j * 8 + 6] = (float)((zq >> 12) & 0xF);
    s_z[j * 8 + 7] = (float)((zq >> 28) & 0xF);
  }
  __syncthreads();
#pragma unroll
  for (int r = 0; r < 2; ++r) {
    const int d = (r << 8) + t;
    const int kk = d >> 3, j = d & 7;
    const int q = qw[(size_t)(k0 + kk) * n8w + (n0 >> 3) + j];
    const int base = j << 3;
    ushort8 o;
    o[0] = f2bf(((float)((q >> 0) & 0xF) - s_z[base + 0]) * s_s[base + 0]);
    o[1] = f2bf(((float)((q >> 16) & 0xF) - s_z[base + 1]) * s_s[base + 1]);
    o[2] = f2bf(((float)((q >> 4) & 0xF) - s_z[base + 2]) * s_s[base + 2]);
    o[3] = f2bf(((float)((q >> 20) & 0xF) - s_z[base + 3]) * s_s[base + 3]);
    o[4] = f2bf(((float)((q >> 8) & 0xF) - s_z[base + 4]) * s_s[base + 4]);
    o[5] = f2bf(((float)((q >> 24) & 0xF) - s_z[base + 5]) * s_s[base + 5]);
    o[6] = f2bf(((float)((q >> 12) & 0xF) - s_z[base + 6]) * s_s[base + 6]);
    o[7] = f2bf(((float)((q >> 28) & 0xF) - s_z[base + 7]) * s_s[base + 7]);
    *(ushort8*)&tile[kk][base] = o;
  }
  __syncthreads();
#pragma unroll
  for (int r = 0; r < 2; ++r) {
    const int d = (r << 8) + t;
    const int nl = d >> 3, seg = d & 7;
    ushort8 o;
#pragma unroll
    for (int i = 0; i < 8; ++i) o[i] = tile[(seg << 3) + i][nl];
    *(ushort8*)&Bt[(size_t)(n0 + nl) * K + k0 + (seg << 3)] = o;
  }
}

// ---------------------------------------------------------------------------
// Kernel 3: 256x256xBK32 triple-buffered bf16 GEMM.  A [M][K], Bt [N][K].
// 8 waves (2M x 4N), per-wave 128x64 output = acc[8][4] f32x4.
// LDS: 3 bufs x (A[256][32] + B[256][32]) = 96 KiB, 1 block/CU.
// Row = 32 shorts = 4 chunks of 16B; physical chunk = logical ^ ((row>>1)&3)
// -> 2-way banks (free).  Staging pre-swizzles the GLOBAL source (linear LDS
// dest, rule #21); reads apply the same XOR.
// Tile t body: vmcnt(4) [buf t landed; t+1's 4 still in flight] -> stage t+2
// -> 12 ds_reads pinned -> lgkmcnt(4) MFMA half1 -> lgkmcnt(0) MFMA half2
// -> barrier.  vmcnt NEVER drains to 0 until the last tile.
// ---------------------------------------------------------------------------
#define BM 256
#define BN 256
#define BK 32

__global__ __launch_bounds__(512, 2) void gemm_bf16(const unsigned short* __restrict__ A,
                                                    const unsigned short* __restrict__ Bt,
                                                    const float* __restrict__ bias,
                                                    float* __restrict__ C,
                                                    int M, int N, int K) {
  __shared__ __align__(16) unsigned short sm[3][16384];  // 96 KiB
  const int tid = threadIdx.x;
  const int w = tid >> 6, lane = tid & 63;
  const int wm = w >> 2, wn = w & 3;

  // cluster mapping (L2 reuse within XCD), as round 6
  const int nbm = M / BM;                       // 16
  const int nbn = N / BN;                       // 43
  const int nclu = ((nbm + 3) >> 2) * ((nbn + 7) >> 3);
  const int xcd = blockIdx.x & 7;
  const int slot = blockIdx.x >> 3;
  const int ci = xcd + 8 * (slot >> 5);
  if (ci >= nclu) return;
  const int t32 = slot & 31;
  const int bm = (ci & 3) * 4 + (t32 & 3);
  const int bn = (ci >> 2) * 8 + (t32 >> 2);
  if (bm >= nbm || bn >= nbn) return;
  const int brow = bm * BM, bcol = bn * BN;

  // staging: wave w covers 32 A-rows and 32 B-rows (2 gload16 each).
  // gload lane -> LDS row base+(lane>>2), phys chunk lane&3.
  // source logical chunk = (lane&3) ^ ((lane>>3)&3)  [= phys ^ ((row>>1)&3)]
  const int srow = lane >> 2;
  const int schunk = (lane & 3) ^ ((lane >> 3) & 3);
  const unsigned short* pA = A + (size_t)(brow + 32 * w + srow) * K + schunk * 8;
  const unsigned short* pB = Bt + (size_t)(bcol + 32 * w + srow) * K + schunk * 8;

  // fragment reads: row r = base + (lane&15), logical chunk = lane>>4,
  // physical chunk = (lane>>4) ^ ((r>>1)&3) = (lane>>4) ^ ((lane>>1)&3).
  const int xk = (lane >> 1) & 3;
  const int aOff = (wm * 128 + (lane & 15)) * 32 + 8 * ((lane >> 4) ^ xk);
  const int bOff = 8192 + (wn * 64 + (lane & 15)) * 32 + 8 * ((lane >> 4) ^ xk);

  const int NKt = K / BK;  // 128

  f32x4 acc[8][4];
#pragma unroll
  for (int m = 0; m < 8; ++m)
#pragma unroll
    for (int n = 0; n < 4; ++n) acc[m][n] = (f32x4){0.f, 0.f, 0.f, 0.f};

  auto stage_tile = [&](int kt) {
    const int buf = kt % 3;
    const size_t k0 = (size_t)kt * BK;
    gload16(pA + k0, &sm[buf][1024 * w]);
    gload16(pA + k0 + (size_t)16 * K, &sm[buf][1024 * w + 512]);
    gload16(pB + k0, &sm[buf][8192 + 1024 * w]);
    gload16(pB + k0 + (size_t)16 * K, &sm[buf][8192 + 1024 * w + 512]);
  };

  // prologue: stage tiles 0 and 1 (8 loads in flight)
  stage_tile(0);
  stage_tile(1);

  for (int t = 0; t < NKt; ++t) {
    const unsigned short* bp = sm[t % 3];

    // gate: buf[t] landed (keeps t+1's 4 loads in flight, steady state)
    if (t < NKt - 1) {
      asm volatile("s_waitcnt vmcnt(4)" ::: "memory");
    } else {
      asm volatile("s_waitcnt vmcnt(0)" ::: "memory");
    }
    __builtin_amdgcn_s_barrier();  // also orders vs prior tile's readers
    __builtin_amdgcn_sched_barrier(0);

    // stage tile t+2 into buf[(t+2)%3] (read last in tile t-1; all waves
    // drained those reads before the barrier above)
    if (t + 2 < NKt) stage_tile(t + 2);
    __builtin_amdgcn_sched_barrier(0);

    // fragment reads, pinned order: a0-3,b0-3 | a4-7
    bf16x8 a[8], b[4];
#pragma unroll
    for (int m = 0; m < 4; ++m)
      a[m] = *(const bf16x8*)(bp + aOff + 512 * m);
#pragma unroll
    for (int n = 0; n < 4; ++n)
      b[n] = *(const bf16x8*)(bp + bOff + 512 * n);
    __builtin_amdgcn_sched_barrier(0);
#pragma unroll
    for (int m = 4; m < 8; ++m)
      a[m] = *(const bf16x8*)(bp + aOff + 512 * m);
    __builtin_amdgcn_sched_barrier(0);

    // half 1: m0-3 x n0-3 (first 8 reads done)
    asm volatile("s_waitcnt lgkmcnt(4)" ::: "memory");
    __builtin_amdgcn_sched_barrier(0);
    __builtin_amdgcn_s_setprio(1);
#pragma unroll
    for (int m = 0; m < 4; ++m)
#pragma unroll
      for (int n = 0; n < 4; ++n)
        acc[m][n] = __builtin_amdgcn_mfma_f32_16x16x32_bf16(a[m], b[n], acc[m][n], 0, 0, 0);
    __builtin_amdgcn_s_setprio(0);
    __builtin_amdgcn_sched_barrier(0);

    // half 2: m4-7 x n0-3
    asm volatile("s_waitcnt lgkmcnt(0)" ::: "memory");
    __builtin_amdgcn_sched_barrier(0);
    __builtin_amdgcn_s_setprio(1);
#pragma unroll
    for (int m = 4; m < 8; ++m)
#pragma unroll
      for (int n = 0; n < 4; ++n)
        acc[m][n] = __builtin_amdgcn_mfma_f32_16x16x32_bf16(a[m], b[n], acc[m][n], 0, 0, 0);
    __builtin_amdgcn_s_setprio(0);
  }
  __builtin_amdgcn_s_barrier();

  // epilogue: C/D layout col=lane&15, row=(lane>>4)*4+reg
#pragma unroll
  for (int n = 0; n < 4; ++n) {
    const int col = bcol + wn * 64 + n * 16 + (lane & 15);
    const float bv = bias[col];
#pragma unroll
    for (int m = 0; m < 8; ++m) {
      const int row0 = brow + wm * 128 + m * 16 + ((lane >> 4) << 2);
#pragma unroll
      for (int q = 0; q < 4; ++q)
        C[(size_t)(row0 + q) * N + col] = acc[m][n][q] + bv;
    }
  }
}

// ---------------------------------------------------------------------------
extern "C" void kernel_launch(void* const* d_in, const int* in_sizes, int n_in,
                              void* d_out, int out_size, void* d_ws, size_t ws_size,
                              hipStream_t stream) {
  const float* x = (const float*)d_in[0];
  const int* qw = (const int*)d_in[1];
  const float* sc = (const float*)d_in[2];
  const int* qz = (const int*)d_in[3];
  const float* bias = (const float*)d_in[4];
  float* out = (float*)d_out;

  const int N = in_sizes[4];                              // 11008
  const int K = (int)(((long long)in_sizes[1] * 8) / N);  // 4096
  const int M = in_sizes[0] / K;                          // 4096

  const size_t a_elems = (size_t)M * K;
  const size_t b_elems = (size_t)N * K;
  const size_t need = (a_elems + b_elems) * sizeof(unsigned short);
  if (ws_size < need) return;

  unsigned short* A = (unsigned short*)d_ws;
  unsigned short* Bt = A + a_elems;

  convert_x<<<2048, 256, 0, stream>>>(x, A, (long long)(a_elems / 8));
  dequant_awq<<<(K / 64) * (N / 64), 256, 0, stream>>>(qw, sc, qz, Bt, K, N);

  const int nbm = M / BM, nbn = N / BN;
  const int nclu = ((nbm + 3) / 4) * ((nbn + 7) / 8);
  const int grid = 8 * 32 * ((nclu + 7) / 8);
  gemm_bf16<<<grid, 512, 0, stream>>>(A, Bt, bias, out, M, N, K);
}